// Round 5
// baseline (72.509 us; speedup 1.0000x reference)
//
#include <hip/hip_runtime.h>

#define B_N 32768
#define H_N 768
#define L_N 10
#define NW_N 30                 // 3 heads x 10 rows
#define KB_N 4                  // K-blocks (768 -> 4 x 192)
#define KPB 192                 // K per block
#define KPW 48                  // K per wave (4 waves/block)
#define SPW 128                 // samples per block/wave-group (64 lanes x 2)

// ---------------- Kernel A: partial grouped-GEMM -> d_ws[kb][B][10] --------
// Weights staged in LDS once per block; each lane carries TWO samples so one
// uniform ds_read_b128 feeds 8 FMAs (ds:fma = 1:8), and 60 live f32
// accumulators keep the allocator in arch-VGPRs (no AGPR round-trips).
__global__ __launch_bounds__(256) void gemm_part(
    const float* __restrict__ hs,
    const float* __restrict__ w1, const float* __restrict__ w2,
    const float* __restrict__ w3,
    const int* __restrict__ groups,
    float* __restrict__ part_out)           // [KB_N][B_N][L_N]
{
    __shared__ __align__(16) unsigned char lds_raw[NW_N * KPB * 4]; // 23040 B
    float* wlds = (float*)lds_raw;                    // [30][KPB]

    const int t    = threadIdx.x;
    const int lane = t & 63;
    const int w    = __builtin_amdgcn_readfirstlane(t >> 6); // wave id 0..3
    const int kb   = blockIdx.x & (KB_N - 1);
    const int sg   = blockIdx.x >> 2;       // sample group (128 samples)
    const int sA   = sg * SPW + lane;       // sample A
    const int sB   = sA + 64;               // sample B

    // ---- stage weight slab [30][KPB] into LDS (coalesced float4) ----
    for (int i = t; i < NW_N * (KPB / 4); i += 256) {
        const int row = i / (KPB / 4);      // 0..29
        const int c4  = i % (KPB / 4);      // 0..47
        const float* src = (row < 10) ? (w1 + row * H_N)
                         : (row < 20) ? (w2 + (row - 10) * H_N)
                                      : (w3 + (row - 20) * H_N);
        const float4 v = *reinterpret_cast<const float4*>(src + kb * KPB + c4 * 4);
        *reinterpret_cast<float4*>(wlds + row * KPB + c4 * 4) = v;
    }

    const int gA = groups[sA];
    const int gB = groups[sB];

    __syncthreads();

    const int wk = w * KPW;
    const float* hrowA = hs + (size_t)sA * H_N + kb * KPB + wk;
    const float* hrowB = hrowA + (size_t)64 * H_N;

    float a0A[L_N], a1A[L_N], a2A[L_N], a0B[L_N], a1B[L_N], a2B[L_N];
    #pragma unroll
    for (int l = 0; l < L_N; ++l) {
        a0A[l] = 0.f; a1A[l] = 0.f; a2A[l] = 0.f;
        a0B[l] = 0.f; a1B[l] = 0.f; a2B[l] = 0.f;
    }

    #pragma unroll 2
    for (int k = 0; k < KPW; k += 4) {
        const float4 hA = *reinterpret_cast<const float4*>(hrowA + k);
        const float4 hB = *reinterpret_cast<const float4*>(hrowB + k);
        #pragma unroll
        for (int l = 0; l < L_N; ++l) {
            const float4 a = *reinterpret_cast<const float4*>(wlds + l * KPB + wk + k);
            const float4 b = *reinterpret_cast<const float4*>(wlds + (l + 10) * KPB + wk + k);
            const float4 c = *reinterpret_cast<const float4*>(wlds + (l + 20) * KPB + wk + k);
            a0A[l] = fmaf(hA.x, a.x, a0A[l]); a0A[l] = fmaf(hA.y, a.y, a0A[l]);
            a0A[l] = fmaf(hA.z, a.z, a0A[l]); a0A[l] = fmaf(hA.w, a.w, a0A[l]);
            a0B[l] = fmaf(hB.x, a.x, a0B[l]); a0B[l] = fmaf(hB.y, a.y, a0B[l]);
            a0B[l] = fmaf(hB.z, a.z, a0B[l]); a0B[l] = fmaf(hB.w, a.w, a0B[l]);
            a1A[l] = fmaf(hA.x, b.x, a1A[l]); a1A[l] = fmaf(hA.y, b.y, a1A[l]);
            a1A[l] = fmaf(hA.z, b.z, a1A[l]); a1A[l] = fmaf(hA.w, b.w, a1A[l]);
            a1B[l] = fmaf(hB.x, b.x, a1B[l]); a1B[l] = fmaf(hB.y, b.y, a1B[l]);
            a1B[l] = fmaf(hB.z, b.z, a1B[l]); a1B[l] = fmaf(hB.w, b.w, a1B[l]);
            a2A[l] = fmaf(hA.x, c.x, a2A[l]); a2A[l] = fmaf(hA.y, c.y, a2A[l]);
            a2A[l] = fmaf(hA.z, c.z, a2A[l]); a2A[l] = fmaf(hA.w, c.w, a2A[l]);
            a2B[l] = fmaf(hB.x, c.x, a2B[l]); a2B[l] = fmaf(hB.y, c.y, a2B[l]);
            a2B[l] = fmaf(hB.z, c.z, a2B[l]); a2B[l] = fmaf(hB.w, c.w, a2B[l]);
        }
    }

    // All waves done reading weights before LDS is repurposed.
    __syncthreads();
    float (*part)[SPW][L_N] = (float (*)[SPW][L_N])lds_raw;  // 20480 B

    #pragma unroll
    for (int l = 0; l < L_N; ++l) {
        part[w][lane][l]      = (gA == 0) ? a0A[l] : ((gA == 1) ? a1A[l] : a2A[l]);
        part[w][lane + 64][l] = (gB == 0) ? a0B[l] : ((gB == 1) ? a1B[l] : a2B[l]);
    }
    __syncthreads();

    if (t < SPW) {
        float* dst = part_out + ((size_t)kb * B_N + sg * SPW + t) * L_N;
        #pragma unroll
        for (int l = 0; l < L_N; l += 2) {
            float2 v;
            v.x = part[0][t][l]   + part[1][t][l]   + part[2][t][l]   + part[3][t][l];
            v.y = part[0][t][l+1] + part[1][t][l+1] + part[2][t][l+1] + part[3][t][l+1];
            *reinterpret_cast<float2*>(dst + l) = v;
        }
    }
}

// ---------------- Kernel B: combine + bias + CE + mean-reduce --------------
__global__ __launch_bounds__(128) void ce_final(
    const float* __restrict__ part_out,
    const float* __restrict__ b1v, const float* __restrict__ b2v,
    const float* __restrict__ b3v,
    const int* __restrict__ groups, const int* __restrict__ labels,
    float* __restrict__ out)
{
    __shared__ float wsum[2];
    const int t = threadIdx.x;
    const int s = blockIdx.x * 128 + t;

    const int g = groups[s];
    const float* bp = (g == 0) ? b1v : ((g == 1) ? b2v : b3v);

    float logit[L_N];
    #pragma unroll
    for (int l = 0; l < L_N; ++l) logit[l] = bp[l];
    #pragma unroll
    for (int kb = 0; kb < KB_N; ++kb) {
        const float2* p = reinterpret_cast<const float2*>(
            part_out + ((size_t)kb * B_N + s) * L_N);
        #pragma unroll
        for (int l = 0; l < L_N / 2; ++l) {
            float2 v = p[l];
            logit[2*l]   += v.x;
            logit[2*l+1] += v.y;
        }
    }

    float m = logit[0];
    #pragma unroll
    for (int l = 1; l < L_N; ++l) m = fmaxf(m, logit[l]);
    float sum = 0.f;
    #pragma unroll
    for (int l = 0; l < L_N; ++l) sum += expf(logit[l] - m);
    const int lab = labels[s];
    float sel = logit[0];
    #pragma unroll
    for (int l = 1; l < L_N; ++l) sel = (lab == l) ? logit[l] : sel;
    float nll = (m + logf(sum)) - sel;

    #pragma unroll
    for (int off = 32; off > 0; off >>= 1)
        nll += __shfl_down(nll, off, 64);
    if ((t & 63) == 0) wsum[t >> 6] = nll;
    __syncthreads();
    if (t == 0) atomicAdd(out, (wsum[0] + wsum[1]) * (1.0f / (float)B_N));
}

// ---------------- Fallback: single-kernel (if ws too small) ----------------
#define SPB 64
#define NCHUNK 8
#define CH (H_N / NCHUNK)

__global__ __launch_bounds__(512, 4) void ce_fused(
    const float* __restrict__ hs,
    const float* __restrict__ w1, const float* __restrict__ b1v,
    const float* __restrict__ w2, const float* __restrict__ b2v,
    const float* __restrict__ w3, const float* __restrict__ b3v,
    const int* __restrict__ groups, const int* __restrict__ labels,
    float* __restrict__ out)
{
    __shared__ float part[NCHUNK][SPB][L_N];
    const int t    = threadIdx.x;
    const int lane = t & 63;
    const int chunk = __builtin_amdgcn_readfirstlane(t >> 6);
    const int s     = blockIdx.x * SPB + lane;

    const float* hrow = hs + (size_t)s * H_N + chunk * CH;
    const float* wp1  = w1 + chunk * CH;
    const float* wp2  = w2 + chunk * CH;
    const float* wp3  = w3 + chunk * CH;

    float acc0[L_N], acc1[L_N], acc2[L_N];
    #pragma unroll
    for (int l = 0; l < L_N; ++l) { acc0[l] = 0.f; acc1[l] = 0.f; acc2[l] = 0.f; }

    #pragma unroll 2
    for (int k = 0; k < CH; k += 4) {
        const float4 h4 = *reinterpret_cast<const float4*>(hrow + k);
        #pragma unroll
        for (int l = 0; l < L_N; ++l) {
            const float4 a = *reinterpret_cast<const float4*>(wp1 + l * H_N + k);
            const float4 b = *reinterpret_cast<const float4*>(wp2 + l * H_N + k);
            const float4 c = *reinterpret_cast<const float4*>(wp3 + l * H_N + k);
            acc0[l] += h4.x * a.x + h4.y * a.y + h4.z * a.z + h4.w * a.w;
            acc1[l] += h4.x * b.x + h4.y * b.y + h4.z * b.z + h4.w * b.w;
            acc2[l] += h4.x * c.x + h4.y * c.y + h4.z * c.z + h4.w * c.w;
        }
    }

    const int g = groups[s];
    #pragma unroll
    for (int l = 0; l < L_N; ++l) {
        float v = (g == 0) ? acc0[l] : ((g == 1) ? acc1[l] : acc2[l]);
        part[chunk][lane][l] = v;
    }
    __syncthreads();

    float nll = 0.f;
    if (t < SPB) {
        const int gg = groups[s];
        const float* bp = (gg == 0) ? b1v : ((gg == 1) ? b2v : b3v);
        float logit[L_N];
        #pragma unroll
        for (int l = 0; l < L_N; ++l) {
            float v = bp[l];
            #pragma unroll
            for (int c = 0; c < NCHUNK; ++c) v += part[c][t][l];
            logit[l] = v;
        }
        float m = logit[0];
        #pragma unroll
        for (int l = 1; l < L_N; ++l) m = fmaxf(m, logit[l]);
        float sum = 0.f;
        #pragma unroll
        for (int l = 0; l < L_N; ++l) sum += expf(logit[l] - m);
        const int lab = labels[s];
        float sel = logit[0];
        #pragma unroll
        for (int l = 1; l < L_N; ++l) sel = (lab == l) ? logit[l] : sel;
        nll = (m + logf(sum)) - sel;
    }
    if (t < 64) {
        #pragma unroll
        for (int off = 32; off > 0; off >>= 1)
            nll += __shfl_down(nll, off, 64);
        if (t == 0) atomicAdd(out, nll * (1.0f / (float)B_N));
    }
}

extern "C" void kernel_launch(void* const* d_in, const int* in_sizes, int n_in,
                              void* d_out, int out_size, void* d_ws, size_t ws_size,
                              hipStream_t stream) {
    const float* hs  = (const float*)d_in[0];
    const float* w1  = (const float*)d_in[1];
    const float* b1v = (const float*)d_in[2];
    const float* w2  = (const float*)d_in[3];
    const float* b2v = (const float*)d_in[4];
    const float* w3  = (const float*)d_in[5];
    const float* b3v = (const float*)d_in[6];
    const int* groups = (const int*)d_in[7];
    const int* labels = (const int*)d_in[8];
    float* out = (float*)d_out;

    hipMemsetAsync(out, 0, sizeof(float), stream);

    const size_t ws_needed = (size_t)KB_N * B_N * L_N * sizeof(float); // 5.24 MB
    if (ws_size >= ws_needed) {
        float* part_out = (float*)d_ws;
        gemm_part<<<(B_N / SPW) * KB_N, 256, 0, stream>>>(
            hs, w1, w2, w3, groups, part_out);
        ce_final<<<B_N / 128, 128, 0, stream>>>(
            part_out, b1v, b2v, b3v, groups, labels, out);
    } else {
        ce_fused<<<B_N / SPB, 512, 0, stream>>>(hs, w1, b1v, w2, b2v, w3, b3v,
                                                groups, labels, out);
    }
}

// Round 6
// 35.493 us; speedup vs baseline: 2.0429x; 2.0429x over previous
//
#include <hip/hip_runtime.h>

#define B_N 32768
#define H_N 768
#define L_N 10
#define M_BLK 64               // samples per block (4 waves x 16 rows)
#define NCOL 32                // output cols padded 30 -> 32
#define NSLOT 96               // 768 / 8 k-slots
#define KSTEPS 24              // 768 / 32

typedef __attribute__((ext_vector_type(8))) short short8v;
typedef __attribute__((ext_vector_type(4))) float float4v;

// round-to-nearest-even f32 -> bf16 bits
static __device__ __forceinline__ short f2bf(float x) {
    unsigned u = __builtin_bit_cast(unsigned, x);
    u += 0x7fffu + ((u >> 16) & 1u);
    return (short)(u >> 16);
}

__global__ __launch_bounds__(256) void fused_mfma_ce(
    const float* __restrict__ hs,
    const float* __restrict__ w1, const float* __restrict__ b1v,
    const float* __restrict__ w2, const float* __restrict__ b2v,
    const float* __restrict__ w3, const float* __restrict__ b3v,
    const int* __restrict__ groups, const int* __restrict__ labels,
    float* __restrict__ out)
{
    // weights bf16, k-slot-major: w[c][k] at wlds[((k/8)*NCOL + c)*8 + k%8]
    __shared__ __align__(16) short wlds[NSLOT * NCOL * 8];   // 48 KB

    const int t  = threadIdx.x;
    const int w  = t >> 6;      // wave 0..3 -> sample sub-tile
    const int l  = t & 63;
    const int cq = l & 15;      // fragment row/col within 16
    const int bq = l >> 4;      // k-chunk group 0..3

    // ---- one-time weight stage: f32 coalesced -> bf16 LDS (rows 30,31 = 0)
    for (int idx = t; idx < NCOL * NSLOT; idx += 256) {
        const int c    = idx / NSLOT;
        const int slot = idx % NSLOT;
        short8v v;
        if (c < 30) {
            const float* src = (c < 10) ? (w1 + c * H_N)
                             : (c < 20) ? (w2 + (c - 10) * H_N)
                                        : (w3 + (c - 20) * H_N);
            const float4 f0 = *reinterpret_cast<const float4*>(src + slot * 8);
            const float4 f1 = *reinterpret_cast<const float4*>(src + slot * 8 + 4);
            v[0] = f2bf(f0.x); v[1] = f2bf(f0.y); v[2] = f2bf(f0.z); v[3] = f2bf(f0.w);
            v[4] = f2bf(f1.x); v[5] = f2bf(f1.y); v[6] = f2bf(f1.z); v[7] = f2bf(f1.w);
        } else {
            v = short8v{0, 0, 0, 0, 0, 0, 0, 0};
        }
        *reinterpret_cast<short8v*>(wlds + (slot * NCOL + c) * 8) = v;
    }
    __syncthreads();

    // ---- K-loop: A direct global->frag (row = m0+cq, k = ks*32 + bq*8) ----
    const int m0 = blockIdx.x * M_BLK + w * 16;
    const float* aptr = hs + (size_t)(m0 + cq) * H_N + bq * 8;
    const short* bb0 = wlds + (bq * NCOL + cq) * 8;          // nf=0 cols 0..15
    const short* bb1 = bb0 + 16 * 8;                          // nf=1 cols 16..31

    float4v acc0 = {0.f, 0.f, 0.f, 0.f};
    float4v acc1 = {0.f, 0.f, 0.f, 0.f};

    #pragma unroll 4
    for (int ks = 0; ks < KSTEPS; ++ks) {
        const float4 f0 = *reinterpret_cast<const float4*>(aptr + ks * 32);
        const float4 f1 = *reinterpret_cast<const float4*>(aptr + ks * 32 + 4);
        short8v a;
        a[0] = f2bf(f0.x); a[1] = f2bf(f0.y); a[2] = f2bf(f0.z); a[3] = f2bf(f0.w);
        a[4] = f2bf(f1.x); a[5] = f2bf(f1.y); a[6] = f2bf(f1.z); a[7] = f2bf(f1.w);
        const short8v b0 = *reinterpret_cast<const short8v*>(bb0 + ks * (NCOL * 4 * 8));
        const short8v b1 = *reinterpret_cast<const short8v*>(bb1 + ks * (NCOL * 4 * 8));
        acc0 = __builtin_amdgcn_mfma_f32_16x16x32_bf16(a, b0, acc0, 0, 0, 0);
        acc1 = __builtin_amdgcn_mfma_f32_16x16x32_bf16(a, b1, acc1, 0, 0, 0);
    }

    // ---- epilogue: logits -> LDS (reuse weight LDS), CE, reduce ----------
    __syncthreads();                     // all waves done reading wlds
    float* slog = (float*)wlds;          // [M_BLK][33]
    #pragma unroll
    for (int r = 0; r < 4; ++r) {        // D row = 4*bq + r, col = cq (+16)
        slog[(w * 16 + bq * 4 + r) * 33 + cq]      = acc0[r];
        slog[(w * 16 + bq * 4 + r) * 33 + cq + 16] = acc1[r];
    }
    __syncthreads();

    float nll = 0.f;
    if (t < M_BLK) {
        const int s   = blockIdx.x * M_BLK + t;
        const int g   = groups[s];
        const int lab = labels[s];
        const float* bp = (g == 0) ? b1v : ((g == 1) ? b2v : b3v);
        float lv[L_N];
        #pragma unroll
        for (int j = 0; j < L_N; ++j)
            lv[j] = slog[t * 33 + g * 10 + j] + bp[j];
        float m = lv[0];
        #pragma unroll
        for (int j = 1; j < L_N; ++j) m = fmaxf(m, lv[j]);
        float sum = 0.f;
        #pragma unroll
        for (int j = 0; j < L_N; ++j) sum += expf(lv[j] - m);
        float sel = lv[0];
        #pragma unroll
        for (int j = 1; j < L_N; ++j) sel = (lab == j) ? lv[j] : sel;
        nll = (m + logf(sum)) - sel;
    }
    if (t < 64) {
        #pragma unroll
        for (int off = 32; off > 0; off >>= 1)
            nll += __shfl_down(nll, off, 64);
        if (t == 0) atomicAdd(out, nll * (1.0f / (float)B_N));
    }
}

extern "C" void kernel_launch(void* const* d_in, const int* in_sizes, int n_in,
                              void* d_out, int out_size, void* d_ws, size_t ws_size,
                              hipStream_t stream) {
    const float* hs  = (const float*)d_in[0];
    const float* w1  = (const float*)d_in[1];
    const float* b1v = (const float*)d_in[2];
    const float* w2  = (const float*)d_in[3];
    const float* b2v = (const float*)d_in[4];
    const float* w3  = (const float*)d_in[5];
    const float* b3v = (const float*)d_in[6];
    const int* groups = (const int*)d_in[7];
    const int* labels = (const int*)d_in[8];
    float* out = (float*)d_out;

    hipMemsetAsync(out, 0, sizeof(float), stream);
    fused_mfma_ce<<<B_N / M_BLK, 256, 0, stream>>>(
        hs, w1, b1v, w2, b2v, w3, b3v, groups, labels, out);
}

// Round 7
// 32.365 us; speedup vs baseline: 2.2404x; 1.0967x over previous
//
#include <hip/hip_runtime.h>

#define B_N 32768
#define H_N 768
#define L_N 10
#define M_BLK 64               // samples per block (4 m-tiles x 16 rows)
#define NCOL 32                // output cols padded 30 -> 32
#define NSLOT 96               // 768 / 8 k-slots
#define KH_STEPS 12            // ksteps per K-half (768 / 32 / 2)

typedef __attribute__((ext_vector_type(8))) short short8v;
typedef __attribute__((ext_vector_type(4))) float float4v;

// round-to-nearest-even f32 -> bf16 bits
static __device__ __forceinline__ short f2bf(float x) {
    unsigned u = __builtin_bit_cast(unsigned, x);
    u += 0x7fffu + ((u >> 16) & 1u);
    return (short)(u >> 16);
}

__global__ __launch_bounds__(512) void fused_mfma_ce(
    const float* __restrict__ hs,
    const float* __restrict__ w1, const float* __restrict__ b1v,
    const float* __restrict__ w2, const float* __restrict__ b2v,
    const float* __restrict__ w3, const float* __restrict__ b3v,
    const int* __restrict__ groups, const int* __restrict__ labels,
    float* __restrict__ out)
{
    // weights bf16, k-slot-major: w[c][k] at wlds[((k/8)*NCOL + c)*8 + k%8]
    __shared__ __align__(16) short wlds[NSLOT * NCOL * 8];   // 48 KB

    const int t  = threadIdx.x;
    const int w  = t >> 6;      // wave 0..7
    const int mt = w & 3;       // m-tile 0..3
    const int kh = w >> 2;      // K-half 0..1
    const int l  = t & 63;
    const int cq = l & 15;      // fragment row/col within 16
    const int bq = l >> 4;      // k-chunk group 0..3

    // ---- one-time weight stage: f32 coalesced -> bf16 LDS (rows 30,31 = 0)
    for (int idx = t; idx < NCOL * NSLOT; idx += 512) {
        const int c    = idx / NSLOT;
        const int slot = idx % NSLOT;
        short8v v;
        if (c < 30) {
            const float* src = (c < 10) ? (w1 + c * H_N)
                             : (c < 20) ? (w2 + (c - 10) * H_N)
                                        : (w3 + (c - 20) * H_N);
            const float4 f0 = *reinterpret_cast<const float4*>(src + slot * 8);
            const float4 f1 = *reinterpret_cast<const float4*>(src + slot * 8 + 4);
            v[0] = f2bf(f0.x); v[1] = f2bf(f0.y); v[2] = f2bf(f0.z); v[3] = f2bf(f0.w);
            v[4] = f2bf(f1.x); v[5] = f2bf(f1.y); v[6] = f2bf(f1.z); v[7] = f2bf(f1.w);
        } else {
            v = short8v{0, 0, 0, 0, 0, 0, 0, 0};
        }
        *reinterpret_cast<short8v*>(wlds + (slot * NCOL + c) * 8) = v;
    }
    __syncthreads();

    // ---- K-half loop: A direct global->frag; B broadcast from LDS --------
    const int m0 = blockIdx.x * M_BLK + mt * 16;
    const float* aptr = hs + (size_t)(m0 + cq) * H_N + kh * (H_N / 2) + bq * 8;
    const short* bb0 = wlds + (((kh * KH_STEPS * 4 + bq) * NCOL) + cq) * 8;
    const short* bb1 = bb0 + 16 * 8;   // cols 16..31

    float4v acc0 = {0.f, 0.f, 0.f, 0.f};
    float4v acc1 = {0.f, 0.f, 0.f, 0.f};

    #pragma unroll 4
    for (int ks = 0; ks < KH_STEPS; ++ks) {
        const float4 f0 = *reinterpret_cast<const float4*>(aptr + ks * 32);
        const float4 f1 = *reinterpret_cast<const float4*>(aptr + ks * 32 + 4);
        short8v a;
        a[0] = f2bf(f0.x); a[1] = f2bf(f0.y); a[2] = f2bf(f0.z); a[3] = f2bf(f0.w);
        a[4] = f2bf(f1.x); a[5] = f2bf(f1.y); a[6] = f2bf(f1.z); a[7] = f2bf(f1.w);
        const short8v b0 = *reinterpret_cast<const short8v*>(bb0 + ks * (NCOL * 4 * 8));
        const short8v b1 = *reinterpret_cast<const short8v*>(bb1 + ks * (NCOL * 4 * 8));
        acc0 = __builtin_amdgcn_mfma_f32_16x16x32_bf16(a, b0, acc0, 0, 0, 0);
        acc1 = __builtin_amdgcn_mfma_f32_16x16x32_bf16(a, b1, acc1, 0, 0, 0);
    }

    // ---- epilogue: K-half partial logits -> LDS, combine, CE, reduce -----
    __syncthreads();                     // all waves done reading wlds
    float (*slog)[M_BLK][33] = (float (*)[M_BLK][33])wlds;   // [2][64][33]
    #pragma unroll
    for (int r = 0; r < 4; ++r) {        // D row = 4*bq + r, col = cq (+16)
        slog[kh][mt * 16 + bq * 4 + r][cq]      = acc0[r];
        slog[kh][mt * 16 + bq * 4 + r][cq + 16] = acc1[r];
    }
    __syncthreads();

    float nll = 0.f;
    if (t < M_BLK) {
        const int s   = blockIdx.x * M_BLK + t;
        const int g   = groups[s];
        const int lab = labels[s];
        const float* bp = (g == 0) ? b1v : ((g == 1) ? b2v : b3v);
        float lv[L_N];
        #pragma unroll
        for (int j = 0; j < L_N; ++j)
            lv[j] = slog[0][t][g * 10 + j] + slog[1][t][g * 10 + j] + bp[j];
        float m = lv[0];
        #pragma unroll
        for (int j = 1; j < L_N; ++j) m = fmaxf(m, lv[j]);
        float sum = 0.f;
        #pragma unroll
        for (int j = 0; j < L_N; ++j) sum += expf(lv[j] - m);
        float sel = lv[0];
        #pragma unroll
        for (int j = 1; j < L_N; ++j) sel = (lab == j) ? lv[j] : sel;
        nll = (m + logf(sum)) - sel;
    }
    if (t < 64) {
        #pragma unroll
        for (int off = 32; off > 0; off >>= 1)
            nll += __shfl_down(nll, off, 64);
        if (t == 0) atomicAdd(out, nll * (1.0f / (float)B_N));
    }
}

extern "C" void kernel_launch(void* const* d_in, const int* in_sizes, int n_in,
                              void* d_out, int out_size, void* d_ws, size_t ws_size,
                              hipStream_t stream) {
    const float* hs  = (const float*)d_in[0];
    const float* w1  = (const float*)d_in[1];
    const float* b1v = (const float*)d_in[2];
    const float* w2  = (const float*)d_in[3];
    const float* b2v = (const float*)d_in[4];
    const float* w3  = (const float*)d_in[5];
    const float* b3v = (const float*)d_in[6];
    const int* groups = (const int*)d_in[7];
    const int* labels = (const int*)d_in[8];
    float* out = (float*)d_out;

    hipMemsetAsync(out, 0, sizeof(float), stream);
    fused_mfma_ce<<<B_N / M_BLK, 512, 0, stream>>>(
        hs, w1, b1v, w2, b2v, w3, b3v, groups, labels, out);
}